// Round 11
// baseline (100.500 us; speedup 1.0000x reference)
//
#include <hip/hip_runtime.h>
#include <stdint.h>

// ScatterND (k=1): out = data.copy(); out[indices[i]] = updates[i]
// data: [1000000,64] f32   indices: [100000,1] i32   updates: [100000,64] f32
//
// R11: R10 mega structure + 32 B/thread copy segment. Each copy thread
// handles two f32x4 from DISTANT halves (j and j+n4/2), so every wave
// instruction remains perfectly lane-contiguous (16 B x 64 lanes), while
// per-thread ILP doubles and total instruction count halves.
//   1. zero_flags    (1 MB)
//   2. flag_scatter  (tiny)
//   3. mega: blocks [0,6250): scatter updates (16 B/thread);
//            blocks [6250,37500): skip-copy (2 x 16 B/thread, split halves).

typedef float f32x4 __attribute__((ext_vector_type(4)));
typedef uint32_t u32x4 __attribute__((ext_vector_type(4)));

__global__ __launch_bounds__(256) void zero_flags_kernel(
    u32x4* __restrict__ p, size_t n16) {
    const size_t i = (size_t)blockIdx.x * blockDim.x + threadIdx.x;
    if (i < n16) p[i] = (u32x4){0u, 0u, 0u, 0u};
}

__global__ __launch_bounds__(256) void flag_scatter_kernel(
    const int* __restrict__ idx, uint8_t* __restrict__ flags, int n) {
    const int t = blockIdx.x * blockDim.x + threadIdx.x;
    if (t < n) flags[idx[t]] = 1;
}

__global__ __launch_bounds__(256) void mega_kernel(
    const f32x4* __restrict__ data,
    const f32x4* __restrict__ upd,
    const int* __restrict__ idx,
    const uint8_t* __restrict__ flags,
    f32x4* __restrict__ out,
    size_t total4,   // update f4 count (scatter segment, 16 B/thread)
    size_t cpHalf) { // n4/2 (copy segment, 2 f4 per thread from both halves)
    const size_t i = (size_t)blockIdx.x * blockDim.x + threadIdx.x;
    if (i < total4) {
        // Scatter segment: block-uniform branch (total4 % 256 == 0).
        const size_t row = i >> 4;
        const size_t col = i & 15;
        const int r = idx[row];
        out[(size_t)r * 16 + col] = upd[i];
    } else {
        const size_t j = i - total4;
        if (j < cpHalf) {
            const size_t j2 = j + cpHalf;
            // Two independent flag checks + loads + stores (MLP-2),
            // each wave instruction lane-contiguous.
            const bool c1 = !flags[j >> 4];
            const bool c2 = !flags[j2 >> 4];
            f32x4 v1, v2;
            if (c1) v1 = data[j];
            if (c2) v2 = data[j2];
            if (c1) out[j] = v1;
            if (c2) out[j2] = v2;
        }
    }
}

// Fallback (ws too small): R8's plain flat copy + scatter.
__global__ __launch_bounds__(256) void copy_flat_kernel(
    const f32x4* __restrict__ src, f32x4* __restrict__ dst, size_t n4) {
    const size_t i = (size_t)blockIdx.x * blockDim.x + threadIdx.x;
    if (i < n4) dst[i] = src[i];
}

__global__ __launch_bounds__(256) void scatter_flat_kernel(
    const int* __restrict__ idx, const f32x4* __restrict__ upd,
    f32x4* __restrict__ out, size_t total4) {
    const size_t i = (size_t)blockIdx.x * blockDim.x + threadIdx.x;
    if (i < total4) {
        const size_t row = i >> 4;
        const size_t col = i & 15;
        const int r = idx[row];
        out[(size_t)r * 16 + col] = upd[i];
    }
}

extern "C" void kernel_launch(void* const* d_in, const int* in_sizes, int n_in,
                              void* d_out, int out_size, void* d_ws, size_t ws_size,
                              hipStream_t stream) {
    const float* data    = (const float*)d_in[0];
    const int*   indices = (const int*)d_in[1];
    const float* updates = (const float*)d_in[2];
    float* out = (float*)d_out;

    const size_t n4          = (size_t)out_size / 4;      // 16M f4
    const size_t num_rows    = (size_t)out_size / 64;     // 1,000,000
    const size_t num_updates = (size_t)in_sizes[2] / 64;  // 100,000
    const size_t total4      = num_updates * 16;          // 1.6M f4

    const int block = 256;
    auto blocks_for = [&](size_t work) {
        return (int)((work + block - 1) / block);
    };

    if (ws_size >= num_rows && (num_rows % 16) == 0 &&
        (total4 % block) == 0 && (n4 % 2) == 0) {
        uint8_t* flags = (uint8_t*)d_ws;
        const size_t n16 = num_rows / 16;
        const size_t cpHalf = n4 / 2;
        zero_flags_kernel<<<blocks_for(n16), block, 0, stream>>>(
            (u32x4*)flags, n16);
        flag_scatter_kernel<<<blocks_for(num_updates), block, 0, stream>>>(
            indices, flags, (int)num_updates);
        mega_kernel<<<blocks_for(total4 + cpHalf), block, 0, stream>>>(
            (const f32x4*)data, (const f32x4*)updates, indices, flags,
            (f32x4*)out, total4, cpHalf);
    } else {
        copy_flat_kernel<<<blocks_for(n4), block, 0, stream>>>(
            (const f32x4*)data, (f32x4*)out, n4);
        scatter_flat_kernel<<<blocks_for(total4), block, 0, stream>>>(
            indices, (const f32x4*)updates, (f32x4*)out, total4);
    }
}